// Round 11
// baseline (49.224 us; speedup 1.0000x reference)
//
#include <hip/hip_runtime.h>
#include <hip/hip_bf16.h>

#define H 768
#define K2P 1600          // 768 + 768 + 64 (width 30 padded to 64)
#define SEQLEN 512
#define NSPAN 128

typedef __attribute__((ext_vector_type(8))) short s16x8;
typedef __attribute__((ext_vector_type(4))) float f32x4;

#define MFMA_BF16 __builtin_amdgcn_mfma_f32_16x16x32_bf16

__device__ __forceinline__ short f2bf(float f) {
    __hip_bfloat16 h = __float2bfloat16(f);
    return *reinterpret_cast<short*>(&h);
}
__device__ __forceinline__ float bf2f(short s) {
    unsigned int u = ((unsigned int)(unsigned short)s) << 16;
    return __builtin_bit_cast(float, u);
}
__device__ __forceinline__ s16x8 cvt8(float4 v0, float4 v1) {
    s16x8 r;
    r[0] = f2bf(v0.x); r[1] = f2bf(v0.y); r[2] = f2bf(v0.z); r[3] = f2bf(v0.w);
    r[4] = f2bf(v1.x); r[5] = f2bf(v1.y); r[6] = f2bf(v1.z); r[7] = f2bf(v1.w);
    return r;
}
// 8 strided fp32 (one weight column, 8 consecutive k) -> bf16 fragment
__device__ __forceinline__ s16x8 ldcol(const float* __restrict__ p) {
    s16x8 t;
    t[0] = f2bf(p[0*H]); t[1] = f2bf(p[1*H]); t[2] = f2bf(p[2*H]); t[3] = f2bf(p[3*H]);
    t[4] = f2bf(p[4*H]); t[5] = f2bf(p[5*H]); t[6] = f2bf(p[6*H]); t[7] = f2bf(p[7*H]);
    return t;
}

// ---------------------------------------------------------------------------
// Shared 32x32 MFMA step (r9-proven). LDS: A rows at [0,4096), B rows at
// [4096,8192); row=128B; XOR swizzle (slot ^ row&7) -> conflict-free b128.
// ---------------------------------------------------------------------------
__device__ __forceinline__ void mstep32(const char* buf, int w, int r, int hi,
                                        f32x4& a0, f32x4& a1)
{
    #pragma unroll
    for (int kc = 0; kc < 2; ++kc) {
        const int ko = kc*64 + hi*16;
        const int ra0 = r, ra1 = 16 + r, rb = w*16 + r;
        s16x8 av0 = *(const s16x8*)(buf + ra0*128 + (ko ^ ((ra0 & 7) << 4)));
        s16x8 av1 = *(const s16x8*)(buf + ra1*128 + (ko ^ ((ra1 & 7) << 4)));
        s16x8 bv  = *(const s16x8*)(buf + 4096 + rb*128 + (ko ^ ((rb & 7) << 4)));
        a0 = MFMA_BF16(av0, bv, a0, 0, 0, 0);
        a1 = MFMA_BF16(av1, bv, a1, 0, 0, 0);
    }
}

#define SWRITE(P, BUF)                                                         \
    *(s16x8*)((BUF) + dA0) = P##0;                                             \
    *(s16x8*)((BUF) + dA1) = P##1;                                             \
    *(s16x8*)((BUF) + dB0) = P##2;                                             \
    *(s16x8*)((BUF) + dB1) = P##3;

// ---------------------------------------------------------------------------
// r9-proven bf16-source GEMM pipeline (used by k2 g2 / k3 g3) — unchanged.
// ---------------------------------------------------------------------------
#define SLOAD(P, K0)                                                           \
    P##0 = *(const s16x8*)(gA0 + (K0));                                        \
    P##1 = *(const s16x8*)(gA1 + (K0));                                        \
    P##2 = *(const s16x8*)(gB0 + (K0));                                        \
    P##3 = *(const s16x8*)(gB1 + (K0));

__device__ __forceinline__ void gemm3232(
    short* ldsb,                       // 2 x 8192 bytes
    const short* __restrict__ A, int ldA, int am0,
    const short* __restrict__ Wt, int ldW, int n0,
    int nsteps, int tid,
    f32x4& a0, f32x4& a1)
{
    const int w = tid >> 6, l = tid & 63;
    const int r = l & 15, hi = l >> 4;

    const int rr = tid >> 3, sl = tid & 7;
    const short* gA0 = A + (size_t)(am0 + rr) * ldA + ((sl ^ (rr & 7)) << 3);
    const short* gA1 = A + (size_t)(am0 + rr + 16) * ldA + ((sl ^ (rr & 7)) << 3);
    const short* gB0 = Wt + (size_t)(n0 + rr) * ldW + ((sl ^ (rr & 7)) << 3);
    const short* gB1 = Wt + (size_t)(n0 + rr + 16) * ldW + ((sl ^ (rr & 7)) << 3);
    const int dA0 = rr*128 + sl*16,        dA1 = (rr+16)*128 + sl*16;
    const int dB0 = 4096 + rr*128 + sl*16, dB1 = 4096 + (rr+16)*128 + sl*16;
    char* b0 = (char*)ldsb;
    char* b1 = (char*)ldsb + 8192;

    s16x8 Pa0, Pa1, Pa2, Pa3;
    s16x8 Pb0, Pb1, Pb2, Pb3;

    SLOAD(Pa, 0)
    SWRITE(Pa, b0)
    SLOAD(Pa, 64)
    __syncthreads();
    for (int s = 0; s < nsteps; s += 2) {
        if (s + 2 < nsteps) { SLOAD(Pb, 64*(s+2)) }
        mstep32(b0, w, r, hi, a0, a1);
        if (s + 1 < nsteps) { SWRITE(Pa, b1) }
        __syncthreads();
        if (s + 1 < nsteps) {
            if (s + 3 < nsteps) { SLOAD(Pa, 64*(s+3)) }
            mstep32(b1, w, r, hi, a0, a1);
            if (s + 2 < nsteps) { SWRITE(Pb, b0) }
            __syncthreads();
        }
    }
}

// ---------------------------------------------------------------------------
// g1 fused pipeline: A staged from seq[idx[row]] (fp32 gather -> cvt),
// B staged from ORIGINAL fp32 W (column reads: lane nl, 8 strided k -> cvt
// -> one swizzled ds_write_b128). Same skeleton / barriers as gemm3232.
// Per step per thread: A 4x float4 + 2 b128 writes; B 16 scalar + 2 b128.
// ---------------------------------------------------------------------------
#define G1LOAD(P, K0)                                                          \
    P##0 = cvt8(*(const float4*)(sA0 + (K0)), *(const float4*)(sA0 + (K0) + 4)); \
    P##1 = cvt8(*(const float4*)(sA1 + (K0)), *(const float4*)(sA1 + (K0) + 4)); \
    P##2 = ldcol(sB0 + (size_t)(K0) * H);                                      \
    P##3 = ldcol(sB1 + (size_t)(K0) * H);

__device__ __forceinline__ void g1pipe(
    short* ldsb, const float* __restrict__ seq, const int* __restrict__ idx,
    int bm, const float* __restrict__ W, int n0w, int tid,
    f32x4& a0, f32x4& a1)
{
    const int w = tid >> 6, l = tid & 63;
    const int r = l & 15, hi = l >> 4;

    const int rr = tid >> 3, sl = tid & 7;
    const int gm0 = bm*32 + rr, gm1 = gm0 + 16;
    const float* sA0 = seq + ((size_t)((gm0 >> 7) * SEQLEN + idx[gm0])) * H
                           + ((sl ^ (rr & 7)) << 3);
    const float* sA1 = seq + ((size_t)((gm1 >> 7) * SEQLEN + idx[gm1])) * H
                           + ((sl ^ (rr & 7)) << 3);
    const int nl = tid & 31, ks0 = tid >> 5;       // kslots ks0 and ks0+4
    const float* sB0 = W + (size_t)(ks0 * 8) * H + n0w + nl;
    const float* sB1 = W + (size_t)((ks0 + 4) * 8) * H + n0w + nl;
    const int dA0 = rr*128 + sl*16, dA1 = (rr+16)*128 + sl*16;
    const int dB0 = 4096 + nl*128 + ((ks0*16)     ^ ((nl & 7) << 4));
    const int dB1 = 4096 + nl*128 + (((ks0+4)*16) ^ ((nl & 7) << 4));
    char* b0 = (char*)ldsb;
    char* b1 = (char*)ldsb + 8192;

    s16x8 Pa0, Pa1, Pa2, Pa3;
    s16x8 Pb0, Pb1, Pb2, Pb3;

    G1LOAD(Pa, 0)
    SWRITE(Pa, b0)
    G1LOAD(Pa, 64)
    __syncthreads();
    for (int s = 0; s < 12; s += 2) {
        if (s + 2 < 12) { G1LOAD(Pb, 64*(s+2)) }
        mstep32(b0, w, r, hi, a0, a1);
        SWRITE(Pa, b1)
        __syncthreads();
        {
            if (s + 3 < 12) { G1LOAD(Pa, 64*(s+3)) }
            mstep32(b1, w, r, hi, a0, a1);
            if (s + 2 < 12) { SWRITE(Pb, b0) }
            __syncthreads();
        }
    }
}

// ---------------------------------------------------------------------------
// K1: blocks [0,768)    : g1 fused (gather + B-transpose from fp32 W)
//     blocks [768,1920) : WtAB = (Wa+Wc | Wb-Wc)^T -> bf16 [n][k]
//     blocks [1920,3120): WtOut^T -> bf16 [768][1600] zero-padded
//     blocks [3120,3136): Xcat width-emb cols 1536..1599
// 128 threads/block.
// ---------------------------------------------------------------------------
__global__ __launch_bounds__(128) void k1(
    const float* __restrict__ seq,
    const int* __restrict__ starts, const int* __restrict__ ends,
    const float* __restrict__ Ws, const float* __restrict__ We,
    const float* __restrict__ bs, const float* __restrict__ be,
    const float* __restrict__ W1, const float* __restrict__ Wout,
    const float* __restrict__ wemb,
    short* __restrict__ Xcat, short* __restrict__ WtAB,
    short* __restrict__ WtOut)
{
    __shared__ __align__(16) short lds[2][4096];
    const int bid = blockIdx.x;
    const int tid = threadIdx.x;

    if (bid < 768) {                      // ---- g1 fused GEMM ----
        const int bm = bid & 15, bn = bid >> 4;
        const int n0 = bn * 32;
        const int* idx = (n0 < 768) ? starts : ends;
        const float* W = (n0 < 768) ? Ws : We;
        const int n0w  = (n0 < 768) ? n0 : n0 - 768;

        f32x4 a0 = {}, a1 = {};
        g1pipe(&lds[0][0], seq, idx, bm, W, n0w, tid, a0, a1);

        const int w = tid >> 6, l = tid & 63;
        const int r = l & 15, hi = l >> 4;
        const int gc = n0 + w*16 + r;
        const float bv = (gc < 768) ? bs[gc] : be[gc - 768];
        const int r0 = bm*32 + hi*4, r1 = r0 + 16;
        #pragma unroll
        for (int rg = 0; rg < 4; ++rg) {
            Xcat[(size_t)(r0 + rg) * K2P + gc] = f2bf(a0[rg] + bv);
            Xcat[(size_t)(r1 + rg) * K2P + gc] = f2bf(a1[rg] + bv);
        }
    } else if (bid < 1920) {              // ---- WtAB transposes ----
        float (*tile)[33] = (float(*)[33])&lds[0][0];
        const int sec = (bid - 768) / 576;            // 0: Wa+Wc, 1: Wb-Wc
        const int t = (bid - 768) % 576;
        const int kt = t / 24, nt = t % 24;
        const int c4 = (tid & 7) << 2;
        const float* base = W1 + (size_t)(sec ? H : 0) * H;
        const float sg = sec ? -1.f : 1.f;
        #pragma unroll
        for (int p = 0; p < 2; ++p) {
            const int kk = p*16 + (tid >> 3);
            const int srow = kt*32 + kk, scol = nt*32 + c4;
            float4 u = *(const float4*)(base + (size_t)srow * H + scol);
            float4 c = *(const float4*)(W1 + (size_t)2*H*H + (size_t)srow * H + scol);
            tile[kk][c4+0] = fmaf(sg, c.x, u.x);
            tile[kk][c4+1] = fmaf(sg, c.y, u.y);
            tile[kk][c4+2] = fmaf(sg, c.z, u.z);
            tile[kk][c4+3] = fmaf(sg, c.w, u.w);
        }
        __syncthreads();
        short* dst = WtAB + (size_t)sec * H * H;
        #pragma unroll
        for (int p = 0; p < 2; ++p) {
            const int nn = p*16 + (tid >> 3);
            short4 o;
            o.x = f2bf(tile[c4+0][nn]); o.y = f2bf(tile[c4+1][nn]);
            o.z = f2bf(tile[c4+2][nn]); o.w = f2bf(tile[c4+3][nn]);
            *(short4*)(dst + (size_t)(nt*32 + nn) * H + kt*32 + c4) = o;
        }
    } else if (bid < 3120) {              // ---- WtOut^T (zero-padded) ----
        float (*tile)[33] = (float(*)[33])&lds[0][0];
        const int t = bid - 1920;
        const int nt = t / 50, kt = t % 50;
        const int c4 = (tid & 7) << 2;
        #pragma unroll
        for (int p = 0; p < 2; ++p) {
            const int kk = p*16 + (tid >> 3);
            const int srow = kt*32 + kk, scol = nt*32 + c4;
            float4 v = make_float4(0.f, 0.f, 0.f, 0.f);
            if (srow < 1566) v = *(const float4*)(Wout + (size_t)srow * H + scol);
            tile[kk][c4+0] = v.x; tile[kk][c4+1] = v.y;
            tile[kk][c4+2] = v.z; tile[kk][c4+3] = v.w;
        }
        __syncthreads();
        #pragma unroll
        for (int p = 0; p < 2; ++p) {
            const int nn = p*16 + (tid >> 3);
            short4 o;
            o.x = f2bf(tile[c4+0][nn]); o.y = f2bf(tile[c4+1][nn]);
            o.z = f2bf(tile[c4+2][nn]); o.w = f2bf(tile[c4+3][nn]);
            *(short4*)(WtOut + (size_t)(nt*32 + nn) * K2P + kt*32 + c4) = o;
        }
    } else {                              // ---- width-emb cols ----
        const int q = bid - 3120;         // 16 blocks x 32 rows
        for (int t = tid; t < 32*64; t += 128) {
            const int row = q*32 + (t >> 6), c = t & 63;
            int wd = ends[row] - starts[row];
            wd = wd < 0 ? 0 : (wd > 10 ? 10 : wd);
            Xcat[(size_t)row * K2P + 1536 + c] = (c < 30) ? f2bf(wemb[wd*30 + c]) : (short)0;
        }
    }
}

// ---------------------------------------------------------------------------
// K2: SR = Xcat(K=1600) @ WtOut^T + b_out   (unchanged r9 g2)
// ---------------------------------------------------------------------------
__global__ __launch_bounds__(128) void k2(
    const short* __restrict__ Xcat, const short* __restrict__ WtOut,
    const float* __restrict__ bout, short* __restrict__ SR)
{
    __shared__ __align__(16) short lds[2][4096];
    const int tid = threadIdx.x;
    const int bm = blockIdx.x, n0 = blockIdx.y * 32;

    f32x4 a0 = {}, a1 = {};
    gemm3232(&lds[0][0], Xcat, K2P, bm*32, WtOut, K2P, n0, 25, tid, a0, a1);

    const int w = tid >> 6, l = tid & 63;
    const int r = l & 15, hi = l >> 4;
    const int gc = n0 + w*16 + r;
    const float bv = bout[gc];
    const int r0 = bm*32 + hi*4, r1 = r0 + 16;
    #pragma unroll
    for (int rg = 0; rg < 4; ++rg) {
        SR[(size_t)(r0 + rg) * H + gc] = f2bf(a0[rg] + bv);
        SR[(size_t)(r1 + rg) * H + gc] = f2bf(a1[rg] + bv);
    }
}

// ---------------------------------------------------------------------------
// K3: y<48: AB[:, gc] = SR @ WtAB^T (+b1 cols<768); y==48: mention (r9 g3)
// ---------------------------------------------------------------------------
__global__ __launch_bounds__(128) void k3(
    const short* __restrict__ SR, const short* __restrict__ WtAB,
    const float* __restrict__ b1, const float* __restrict__ Wm,
    const float* __restrict__ bment,
    float* __restrict__ AB, float* __restrict__ mention)
{
    const int tid = threadIdx.x;
    const int bm = blockIdx.x;

    if (blockIdx.y == 48) {               // mention scores, 32 rows per block
        const int w = tid >> 6, l = tid & 63;
        const int rows0 = bm*32 + w*16;
        const float bm_add = bment[0];
        for (int rr = 0; rr < 16; ++rr) {
            const int row = rows0 + rr;
            float p = 0.f;
            #pragma unroll
            for (int kk = 0; kk < 12; ++kk) {
                const int k = kk*64 + l;
                p = fmaf(bf2f(SR[(size_t)row * H + k]), Wm[k], p);
            }
            #pragma unroll
            for (int off = 32; off; off >>= 1) p += __shfl_down(p, off);
            if (l == 0) mention[row] = p + bm_add;
        }
        return;
    }

    __shared__ __align__(16) short lds[2][4096];
    const int n0 = blockIdx.y * 32;

    f32x4 a0 = {}, a1 = {};
    gemm3232(&lds[0][0], SR, H, bm*32, WtAB, H, n0, 12, tid, a0, a1);

    const int w = tid >> 6, l = tid & 63;
    const int r = l & 15, hi = l >> 4;
    const int gc = n0 + w*16 + r;
    const float bv = (gc < 768) ? b1[gc] : 0.f;
    const int r0 = bm*32 + hi*4, r1 = r0 + 16;
    #pragma unroll
    for (int rg = 0; rg < 4; ++rg) {
        AB[(size_t)(r0 + rg) * 1536 + gc] = a0[rg] + bv;
        AB[(size_t)(r1 + rg) * 1536 + gc] = a1[rg] + bv;
    }
}

// ---------------------------------------------------------------------------
// K4: pair[b,i,j] = (j<i) ? sum_h relu(AI+BJ)*W2[h] + b2 : 0  (unchanged)
// ---------------------------------------------------------------------------
__global__ __launch_bounds__(256) void k4(
    const float* __restrict__ AB, const float* __restrict__ W2,
    const float* __restrict__ b2, float* __restrict__ pair)
{
    const int tid = threadIdx.x;
    const int bx = blockIdx.x & 7, by = blockIdx.x >> 3;
    const int bz = blockIdx.y;

    const int tx = tid & 15, ty = tid >> 4;
    const int i = by * 16 + ty, j = bx * 16 + tx;
    float* outp = pair + ((size_t)bz * NSPAN + i) * NSPAN + j;

    if (bx > by) { *outp = 0.f; return; }

    __shared__ __align__(16) float Ais[16][68];
    __shared__ __align__(16) float Bjs[16][68];
    __shared__ __align__(16) float w2s[768];
    for (int q = tid; q < 768; q += 256) w2s[q] = W2[q];

    const int sr = tid >> 4, sc = (tid & 15) << 2;
    const float* aSrc = AB + ((size_t)bz*NSPAN + by*16 + sr)*1536 + sc;
    const float* bSrc = AB + ((size_t)bz*NSPAN + bx*16 + sr)*1536 + 768 + sc;
    float acc = 0.f;

    float4 ra = *(const float4*)(aSrc);
    float4 rb = *(const float4*)(bSrc);

    for (int ch = 0; ch < 12; ++ch) {
        __syncthreads();
        *(float4*)&Ais[sr][sc] = ra;
        *(float4*)&Bjs[sr][sc] = rb;
        __syncthreads();
        if (ch < 11) {
            ra = *(const float4*)(aSrc + (ch+1)*64);
            rb = *(const float4*)(bSrc + (ch+1)*64);
        }
        #pragma unroll
        for (int hq = 0; hq < 16; ++hq) {
            float4 a = *(const float4*)&Ais[ty][hq << 2];
            float4 b = *(const float4*)&Bjs[tx][hq << 2];
            float4 wv = *(const float4*)&w2s[ch*64 + (hq << 2)];
            acc = fmaf(fmaxf(a.x + b.x, 0.f), wv.x, acc);
            acc = fmaf(fmaxf(a.y + b.y, 0.f), wv.y, acc);
            acc = fmaf(fmaxf(a.z + b.z, 0.f), wv.z, acc);
            acc = fmaf(fmaxf(a.w + b.w, 0.f), wv.w, acc);
        }
    }
    *outp = (j < i) ? (acc + b2[0]) : 0.f;
}

// ---------------------------------------------------------------------------
extern "C" void kernel_launch(void* const* d_in, const int* in_sizes, int n_in,
                              void* d_out, int out_size, void* d_ws, size_t ws_size,
                              hipStream_t stream)
{
    const float* seq    = (const float*)d_in[0];
    const int*   starts = (const int*)  d_in[1];
    const int*   ends   = (const int*)  d_in[2];
    const float* Ws     = (const float*)d_in[3];
    const float* bs     = (const float*)d_in[4];
    const float* We     = (const float*)d_in[5];
    const float* be     = (const float*)d_in[6];
    const float* wemb   = (const float*)d_in[7];
    const float* Wout   = (const float*)d_in[8];
    const float* bout   = (const float*)d_in[9];
    const float* Wm     = (const float*)d_in[10];
    const float* bment  = (const float*)d_in[11];
    const float* W1     = (const float*)d_in[12];
    const float* b1     = (const float*)d_in[13];
    const float* W2     = (const float*)d_in[14];
    const float* b2     = (const float*)d_in[15];

    float* ws = (float*)d_ws;
    float* AB    = ws;                          // 512*1536 fp32
    short* Xcat  = (short*)(ws + 786432);       // 512*1600 bf16
    short* SR    = Xcat + 819200;               // 512*768  bf16
    short* WtAB  = SR + 393216;                 // 1536*768 bf16
    short* WtOut = WtAB + 1179648;              // 768*1600 bf16

    float* out_mention = (float*)d_out;         // 512
    float* out_pair    = (float*)d_out + 512;   // 4*128*128

    hipLaunchKernelGGL(k1, dim3(3136), dim3(128), 0, stream,
                       seq, starts, ends, Ws, We, bs, be, W1, Wout, wemb,
                       Xcat, WtAB, WtOut);
    hipLaunchKernelGGL(k2, dim3(16, 24), dim3(128), 0, stream,
                       Xcat, WtOut, bout, SR);
    hipLaunchKernelGGL(k3, dim3(16, 49), dim3(128), 0, stream,
                       SR, WtAB, b1, Wm, bment, AB, out_mention);
    hipLaunchKernelGGL(k4, dim3(64, 4), dim3(256), 0, stream,
                       AB, W2, b2, out_pair);
}

// Round 12
// 48.364 us; speedup vs baseline: 1.0178x; 1.0178x over previous
//
#include <hip/hip_runtime.h>
#include <hip/hip_bf16.h>

#define H 768
#define K2P 1664          // 768 + 768 + 128 (width 30 padded; 26 K-steps = 13+13)
#define SEQLEN 512
#define NSPAN 128

typedef __attribute__((ext_vector_type(8))) short s16x8;
typedef __attribute__((ext_vector_type(4))) float f32x4;

#define MFMA_BF16 __builtin_amdgcn_mfma_f32_16x16x32_bf16

__device__ __forceinline__ short f2bf(float f) {
    __hip_bfloat16 h = __float2bfloat16(f);
    return *reinterpret_cast<short*>(&h);
}
__device__ __forceinline__ float bf2f(short s) {
    unsigned int u = ((unsigned int)(unsigned short)s) << 16;
    return __builtin_bit_cast(float, u);
}

// ---------------------------------------------------------------------------
// 32x32 MFMA step (r9-proven). buf: A rows at [0,4096), B rows at [4096,8192);
// row = 128B; XOR swizzle (slot ^ row&7) -> conflict-free ds_read_b128.
// ---------------------------------------------------------------------------
__device__ __forceinline__ void mstep32(const char* buf, int w, int r, int hi,
                                        f32x4& a0, f32x4& a1)
{
    #pragma unroll
    for (int kc = 0; kc < 2; ++kc) {
        const int ko = kc*64 + hi*16;
        const int ra0 = r, ra1 = 16 + r, rb = w*16 + r;
        s16x8 av0 = *(const s16x8*)(buf + ra0*128 + (ko ^ ((ra0 & 7) << 4)));
        s16x8 av1 = *(const s16x8*)(buf + ra1*128 + (ko ^ ((ra1 & 7) << 4)));
        s16x8 bv  = *(const s16x8*)(buf + 4096 + rb*128 + (ko ^ ((rb & 7) << 4)));
        a0 = MFMA_BF16(av0, bv, a0, 0, 0, 0);
        a1 = MFMA_BF16(av1, bv, a1, 0, 0, 0);
    }
}

#define SLOAD(P, K0)                                                           \
    P##0 = *(const s16x8*)(gA0 + (K0));                                        \
    P##1 = *(const s16x8*)(gA1 + (K0));                                        \
    P##2 = *(const s16x8*)(gB0 + (K0));                                        \
    P##3 = *(const s16x8*)(gB1 + (K0));

#define SWRITE(P, BUF)                                                         \
    *(s16x8*)((BUF) + dA0) = P##0;                                             \
    *(s16x8*)((BUF) + dA1) = P##1;                                             \
    *(s16x8*)((BUF) + dB0) = P##2;                                             \
    *(s16x8*)((BUF) + dB1) = P##3;

// ---------------------------------------------------------------------------
// Split-K 32x32 GEMM: 256 threads = 2 wave-pairs; pair pr handles K range
// [pr*halfsteps*64, ...). Each pair = r9's proven reg-staged double-buffer
// pipeline in its own 16KB LDS region; identical control flow for both pairs
// -> every __syncthreads is uniform (same race-free class as rounds 7/9).
// Epilogue: pair1 publishes acc via LDS; pair0 adds and returns (caller
// stores from tid<128 only).
// ---------------------------------------------------------------------------
__device__ __forceinline__ void gemm_sk(
    short* ldsb,                       // 4 x 8192 B
    const short* __restrict__ A, int ldA, int am0,
    const short* __restrict__ Wt, int ldW, int n0,
    int halfsteps, int tid,
    f32x4& a0, f32x4& a1)
{
    const int pr = tid >> 7, pt = tid & 127;
    const int w = pt >> 6, l = pt & 63;
    const int r = l & 15, hi = l >> 4;
    const int kof = pr * halfsteps * 64;

    const int rr = pt >> 3, sl = pt & 7;
    const short* gA0 = A + (size_t)(am0 + rr) * ldA + kof + ((sl ^ (rr & 7)) << 3);
    const short* gA1 = A + (size_t)(am0 + rr + 16) * ldA + kof + ((sl ^ (rr & 7)) << 3);
    const short* gB0 = Wt + (size_t)(n0 + rr) * ldW + kof + ((sl ^ (rr & 7)) << 3);
    const short* gB1 = Wt + (size_t)(n0 + rr + 16) * ldW + kof + ((sl ^ (rr & 7)) << 3);
    const int dA0 = rr*128 + sl*16,        dA1 = (rr+16)*128 + sl*16;
    const int dB0 = 4096 + rr*128 + sl*16, dB1 = 4096 + (rr+16)*128 + sl*16;
    char* b0 = (char*)ldsb + pr*16384;
    char* b1 = b0 + 8192;

    s16x8 Pa0, Pa1, Pa2, Pa3;
    s16x8 Pb0, Pb1, Pb2, Pb3;

    SLOAD(Pa, 0)
    SWRITE(Pa, b0)
    SLOAD(Pa, 64)
    __syncthreads();
    for (int s = 0; s < halfsteps; s += 2) {
        if (s + 2 < halfsteps) { SLOAD(Pb, 64*(s+2)) }
        mstep32(b0, w, r, hi, a0, a1);
        if (s + 1 < halfsteps) { SWRITE(Pa, b1) }
        __syncthreads();
        if (s + 1 < halfsteps) {
            if (s + 3 < halfsteps) { SLOAD(Pa, 64*(s+3)) }
            mstep32(b1, w, r, hi, a0, a1);
            if (s + 2 < halfsteps) { SWRITE(Pb, b0) }
            __syncthreads();
        }
    }
    // cross-pair K reduction (LDS reuse is safe: loop ends on a barrier)
    float* red = (float*)ldsb;
    if (pr) {
        *(f32x4*)(red + pt*8)     = a0;
        *(f32x4*)(red + pt*8 + 4) = a1;
    }
    __syncthreads();
    if (!pr) {
        a0 += *(const f32x4*)(red + pt*8);
        a1 += *(const f32x4*)(red + pt*8 + 4);
    }
}

// ---------------------------------------------------------------------------
// P0: weight transposes -> bf16 [n][k]; gather seq -> Xg bf16; width cols.
// blocks: [0,2304) Ws/We/Wa+Wc/Wb-Wc | [2304,3552) WtOut^T (1664-padded) |
//         [3552,3808) gather | [3808,3824) Xcat width cols 1536..1663
// ---------------------------------------------------------------------------
__global__ __launch_bounds__(256) void k_prep(
    const float* __restrict__ seq,
    const int* __restrict__ starts, const int* __restrict__ ends,
    const float* __restrict__ Ws, const float* __restrict__ We,
    const float* __restrict__ W1, const float* __restrict__ Wout,
    const float* __restrict__ wemb,
    short* __restrict__ WtSE, short* __restrict__ WtAB,
    short* __restrict__ WtOut, short* __restrict__ Xg, short* __restrict__ Xcat)
{
    const int b = blockIdx.x;
    const int tid = threadIdx.x;

    if (b < 2304) {                       // Ws/We/Wa+Wc/Wb-Wc transposes
        const int sec = b / 576;
        const int t = b % 576;
        const int kt = t / 24, nt = t % 24;
        __shared__ float tile[32][33];
        const int kk = tid >> 3;
        const int c4 = (tid & 7) << 2;
        const int srow = kt * 32 + kk, scol = nt * 32 + c4;
        float4 v;
        if (sec == 0)      v = *(const float4*)(Ws + (size_t)srow * H + scol);
        else if (sec == 1) v = *(const float4*)(We + (size_t)srow * H + scol);
        else {
            const float* base = W1 + (size_t)(sec == 2 ? 0 : H) * H;
            float4 u = *(const float4*)(base + (size_t)srow * H + scol);
            float4 c = *(const float4*)(W1 + (size_t)2*H*H + (size_t)srow * H + scol);
            const float sg = (sec == 2) ? 1.f : -1.f;
            v = make_float4(fmaf(sg,c.x,u.x), fmaf(sg,c.y,u.y),
                            fmaf(sg,c.z,u.z), fmaf(sg,c.w,u.w));
        }
        tile[kk][c4+0]=v.x; tile[kk][c4+1]=v.y; tile[kk][c4+2]=v.z; tile[kk][c4+3]=v.w;
        __syncthreads();
        short* dst = (sec < 2 ? WtSE : WtAB) + (size_t)(sec & 1) * H * H;
        const int nn = tid >> 3;
        short4 o;
        o.x = f2bf(tile[c4+0][nn]); o.y = f2bf(tile[c4+1][nn]);
        o.z = f2bf(tile[c4+2][nn]); o.w = f2bf(tile[c4+3][nn]);
        *(short4*)(dst + (size_t)(nt*32 + nn) * H + kt*32 + c4) = o;
    } else if (b < 3552) {                // Wout^T -> [768][1664], zero-padded
        const int t = b - 2304;
        const int nt = t / 52, kt = t % 52;
        __shared__ float tile[32][33];
        const int kk = tid >> 3;
        const int c4 = (tid & 7) << 2;
        const int srow = kt * 32 + kk, scol = nt * 32 + c4;
        float4 v = make_float4(0.f, 0.f, 0.f, 0.f);
        if (srow < 1566) v = *(const float4*)(Wout + (size_t)srow * H + scol);
        tile[kk][c4+0]=v.x; tile[kk][c4+1]=v.y; tile[kk][c4+2]=v.z; tile[kk][c4+3]=v.w;
        __syncthreads();
        const int nn = tid >> 3;
        short4 o;
        o.x = f2bf(tile[c4+0][nn]); o.y = f2bf(tile[c4+1][nn]);
        o.z = f2bf(tile[c4+2][nn]); o.w = f2bf(tile[c4+3][nn]);
        *(short4*)(WtOut + (size_t)(nt*32 + nn) * K2P + kt*32 + c4) = o;
    } else if (b < 3808) {                // gather: Xg[0:512)=starts, [512:1024)=ends
        const int gr = (b - 3552) * 4 + (tid >> 6);
        const int c = tid & 63;
        const int spanrow = gr & 511;
        const int idx = (gr < 512) ? starts[spanrow] : ends[spanrow];
        const size_t base = ((size_t)(spanrow >> 7) * SEQLEN + idx) * H;
        #pragma unroll
        for (int i = 0; i < 12; ++i) {
            const int col = c + i*64;
            Xg[(size_t)gr * H + col] = f2bf(seq[base + col]);
        }
    } else {                              // Xcat width-emb cols 1536..1663
        const int q = b - 3808;           // 16 blocks x 32 rows x 128 cols
        for (int t = tid; t < 32*128; t += 256) {
            const int row = q*32 + (t >> 7), c = t & 127;
            int wd = ends[row] - starts[row];
            wd = wd < 0 ? 0 : (wd > 10 ? 10 : wd);
            Xcat[(size_t)row * K2P + 1536 + c] = (c < 30) ? f2bf(wemb[wd*30 + c]) : (short)0;
        }
    }
}

// ---------------------------------------------------------------------------
// G1: Xcat[:, gc] = Xg(half) @ WtSE^T + bias   (split-K 6+6)
// ---------------------------------------------------------------------------
__global__ __launch_bounds__(256) void k_g1(
    const short* __restrict__ Xg, const short* __restrict__ WtSE,
    const float* __restrict__ bs, const float* __restrict__ be,
    short* __restrict__ Xcat)
{
    __shared__ __align__(16) short lds[4][4096];
    const int tid = threadIdx.x;
    const int bm = blockIdx.x, n0 = blockIdx.y * 32;
    const int am0 = (n0 >= 768 ? 512 : 0) + bm * 32;

    f32x4 a0 = {}, a1 = {};
    gemm_sk(&lds[0][0], Xg, H, am0, WtSE, H, n0, 6, tid, a0, a1);

    if (tid < 128) {
        const int w = tid >> 6, l = tid & 63;
        const int r = l & 15, hi = l >> 4;
        const int gc = n0 + w*16 + r;
        const float bv = (gc < 768) ? bs[gc] : be[gc - 768];
        const int r0 = bm*32 + hi*4, r1 = r0 + 16;
        #pragma unroll
        for (int rg = 0; rg < 4; ++rg) {
            Xcat[(size_t)(r0 + rg) * K2P + gc] = f2bf(a0[rg] + bv);
            Xcat[(size_t)(r1 + rg) * K2P + gc] = f2bf(a1[rg] + bv);
        }
    }
}

// ---------------------------------------------------------------------------
// G2: SR = Xcat(K=1664) @ WtOut^T + b_out   (split-K 13+13)
// ---------------------------------------------------------------------------
__global__ __launch_bounds__(256) void k_g2(
    const short* __restrict__ Xcat, const short* __restrict__ WtOut,
    const float* __restrict__ bout, short* __restrict__ SR)
{
    __shared__ __align__(16) short lds[4][4096];
    const int tid = threadIdx.x;
    const int bm = blockIdx.x, n0 = blockIdx.y * 32;

    f32x4 a0 = {}, a1 = {};
    gemm_sk(&lds[0][0], Xcat, K2P, bm*32, WtOut, K2P, n0, 13, tid, a0, a1);

    if (tid < 128) {
        const int w = tid >> 6, l = tid & 63;
        const int r = l & 15, hi = l >> 4;
        const int gc = n0 + w*16 + r;
        const float bv = bout[gc];
        const int r0 = bm*32 + hi*4, r1 = r0 + 16;
        #pragma unroll
        for (int rg = 0; rg < 4; ++rg) {
            SR[(size_t)(r0 + rg) * H + gc] = f2bf(a0[rg] + bv);
            SR[(size_t)(r1 + rg) * H + gc] = f2bf(a1[rg] + bv);
        }
    }
}

// ---------------------------------------------------------------------------
// G3: y<48: AB[:, gc] = SR @ WtAB^T (+b1 cols<768) [split-K 6+6]
//     y==48: mention = SR @ Wm + b_ment
// ---------------------------------------------------------------------------
__global__ __launch_bounds__(256) void k_g3(
    const short* __restrict__ SR, const short* __restrict__ WtAB,
    const float* __restrict__ b1, const float* __restrict__ Wm,
    const float* __restrict__ bment,
    float* __restrict__ AB, float* __restrict__ mention)
{
    const int tid = threadIdx.x;
    const int bm = blockIdx.x;

    if (blockIdx.y == 48) {               // mention scores, 32 rows per block
        const int w4 = tid >> 6, l = tid & 63;
        const int rows0 = bm*32 + w4*8;
        const float bm_add = bment[0];
        for (int rr = 0; rr < 8; ++rr) {
            const int row = rows0 + rr;
            float p = 0.f;
            #pragma unroll
            for (int kk = 0; kk < 12; ++kk) {
                const int k = kk*64 + l;
                p = fmaf(bf2f(SR[(size_t)row * H + k]), Wm[k], p);
            }
            #pragma unroll
            for (int off = 32; off; off >>= 1) p += __shfl_down(p, off);
            if (l == 0) mention[row] = p + bm_add;
        }
        return;
    }

    __shared__ __align__(16) short lds[4][4096];
    const int n0 = blockIdx.y * 32;

    f32x4 a0 = {}, a1 = {};
    gemm_sk(&lds[0][0], SR, H, bm*32, WtAB, H, n0, 6, tid, a0, a1);

    if (tid < 128) {
        const int w = tid >> 6, l = tid & 63;
        const int r = l & 15, hi = l >> 4;
        const int gc = n0 + w*16 + r;
        const float bv = (gc < 768) ? b1[gc] : 0.f;
        const int r0 = bm*32 + hi*4, r1 = r0 + 16;
        #pragma unroll
        for (int rg = 0; rg < 4; ++rg) {
            AB[(size_t)(r0 + rg) * 1536 + gc] = a0[rg] + bv;
            AB[(size_t)(r1 + rg) * 1536 + gc] = a1[rg] + bv;
        }
    }
}

// ---------------------------------------------------------------------------
// G4: pair[b,i,j] = (j<i) ? sum_h relu(AI+BJ)*W2[h] + b2 : 0  (unchanged r9)
// ---------------------------------------------------------------------------
__global__ __launch_bounds__(256) void k_pair(
    const float* __restrict__ AB, const float* __restrict__ W2,
    const float* __restrict__ b2, float* __restrict__ pair)
{
    const int tid = threadIdx.x;
    const int bx = blockIdx.x & 7, by = blockIdx.x >> 3;
    const int bz = blockIdx.y;

    const int tx = tid & 15, ty = tid >> 4;
    const int i = by * 16 + ty, j = bx * 16 + tx;
    float* outp = pair + ((size_t)bz * NSPAN + i) * NSPAN + j;

    if (bx > by) { *outp = 0.f; return; }

    __shared__ __align__(16) float Ais[16][68];
    __shared__ __align__(16) float Bjs[16][68];
    __shared__ __align__(16) float w2s[768];
    for (int q = tid; q < 768; q += 256) w2s[q] = W2[q];

    const int sr = tid >> 4, sc = (tid & 15) << 2;
    const float* aSrc = AB + ((size_t)bz*NSPAN + by*16 + sr)*1536 + sc;
    const float* bSrc = AB + ((size_t)bz*NSPAN + bx*16 + sr)*1536 + 768 + sc;
    float acc = 0.f;

    float4 ra = *(const float4*)(aSrc);
    float4 rb = *(const float4*)(bSrc);

    for (int ch = 0; ch < 12; ++ch) {
        __syncthreads();
        *(float4*)&Ais[sr][sc] = ra;
        *(float4*)&Bjs[sr][sc] = rb;
        __syncthreads();
        if (ch < 11) {
            ra = *(const float4*)(aSrc + (ch+1)*64);
            rb = *(const float4*)(bSrc + (ch+1)*64);
        }
        #pragma unroll
        for (int hq = 0; hq < 16; ++hq) {
            float4 a = *(const float4*)&Ais[ty][hq << 2];
            float4 b = *(const float4*)&Bjs[tx][hq << 2];
            float4 wv = *(const float4*)&w2s[ch*64 + (hq << 2)];
            acc = fmaf(fmaxf(a.x + b.x, 0.f), wv.x, acc);
            acc = fmaf(fmaxf(a.y + b.y, 0.f), wv.y, acc);
            acc = fmaf(fmaxf(a.z + b.z, 0.f), wv.z, acc);
            acc = fmaf(fmaxf(a.w + b.w, 0.f), wv.w, acc);
        }
    }
    *outp = (j < i) ? (acc + b2[0]) : 0.f;
}

// ---------------------------------------------------------------------------
extern "C" void kernel_launch(void* const* d_in, const int* in_sizes, int n_in,
                              void* d_out, int out_size, void* d_ws, size_t ws_size,
                              hipStream_t stream)
{
    const float* seq    = (const float*)d_in[0];
    const int*   starts = (const int*)  d_in[1];
    const int*   ends   = (const int*)  d_in[2];
    const float* Ws     = (const float*)d_in[3];
    const float* bs     = (const float*)d_in[4];
    const float* We     = (const float*)d_in[5];
    const float* be     = (const float*)d_in[6];
    const float* wemb   = (const float*)d_in[7];
    const float* Wout   = (const float*)d_in[8];
    const float* bout   = (const float*)d_in[9];
    const float* Wm     = (const float*)d_in[10];
    const float* bment  = (const float*)d_in[11];
    const float* W1     = (const float*)d_in[12];
    const float* b1     = (const float*)d_in[13];
    const float* W2     = (const float*)d_in[14];
    const float* b2     = (const float*)d_in[15];

    float* ws = (float*)d_ws;
    float* AB    = ws;                          // 512*1536 fp32
    short* Xg    = (short*)(ws + 786432);       // 1024*768 bf16
    short* Xcat  = Xg + 786432;                 // 512*1664 bf16
    short* SR    = Xcat + 851968;               // 512*768  bf16
    short* WtSE  = SR + 393216;                 // 1536*768 bf16
    short* WtAB  = WtSE + 1179648;              // 1536*768 bf16
    short* WtOut = WtAB + 1179648;              // 768*1664 bf16

    float* out_mention = (float*)d_out;         // 512
    float* out_pair    = (float*)d_out + 512;   // 4*128*128

    hipLaunchKernelGGL(k_prep, dim3(3824), dim3(256), 0, stream,
                       seq, starts, ends, Ws, We, W1, Wout, wemb,
                       WtSE, WtAB, WtOut, Xg, Xcat);
    hipLaunchKernelGGL(k_g1, dim3(16, 48), dim3(256), 0, stream,
                       Xg, WtSE, bs, be, Xcat);
    hipLaunchKernelGGL(k_g2, dim3(16, 24), dim3(256), 0, stream,
                       Xcat, WtOut, bout, SR);
    hipLaunchKernelGGL(k_g3, dim3(16, 49), dim3(256), 0, stream,
                       SR, WtAB, b1, Wm, bment, AB, out_mention);
    hipLaunchKernelGGL(k_pair, dim3(64, 4), dim3(256), 0, stream,
                       AB, W2, b2, out_pair);
}

// Round 13
// 47.981 us; speedup vs baseline: 1.0259x; 1.0080x over previous
//
#include <hip/hip_runtime.h>
#include <hip/hip_bf16.h>

#define H 768
#define K2P 1600          // 768 + 768 + 64 (width 30 padded to 64)
#define SEQLEN 512
#define NSPAN 128

typedef __attribute__((ext_vector_type(8))) short s16x8;
typedef __attribute__((ext_vector_type(4))) float f32x4;

#define MFMA_BF16 __builtin_amdgcn_mfma_f32_16x16x32_bf16

__device__ __forceinline__ short f2bf(float f) {
    __hip_bfloat16 h = __float2bfloat16(f);
    return *reinterpret_cast<short*>(&h);
}
__device__ __forceinline__ float bf2f(short s) {
    unsigned int u = ((unsigned int)(unsigned short)s) << 16;
    return __builtin_bit_cast(float, u);
}

// ---------------------------------------------------------------------------
// 32x32 MFMA step (r9-proven). buf: A rows at [0,4096), B rows at [4096,8192);
// row = 128B; XOR swizzle (slot ^ row&7) -> conflict-free ds_read_b128.
// ---------------------------------------------------------------------------
__device__ __forceinline__ void mstep32(const char* buf, int w, int r, int hi,
                                        f32x4& a0, f32x4& a1)
{
    #pragma unroll
    for (int kc = 0; kc < 2; ++kc) {
        const int ko = kc*64 + hi*16;
        const int ra0 = r, ra1 = 16 + r, rb = w*16 + r;
        s16x8 av0 = *(const s16x8*)(buf + ra0*128 + (ko ^ ((ra0 & 7) << 4)));
        s16x8 av1 = *(const s16x8*)(buf + ra1*128 + (ko ^ ((ra1 & 7) << 4)));
        s16x8 bv  = *(const s16x8*)(buf + 4096 + rb*128 + (ko ^ ((rb & 7) << 4)));
        a0 = MFMA_BF16(av0, bv, a0, 0, 0, 0);
        a1 = MFMA_BF16(av1, bv, a1, 0, 0, 0);
    }
}

#define SLOAD(P, K0)                                                           \
    P##0 = *(const s16x8*)(gA0 + (K0));                                        \
    P##1 = *(const s16x8*)(gA1 + (K0));                                        \
    P##2 = *(const s16x8*)(gB0 + (K0));                                        \
    P##3 = *(const s16x8*)(gB1 + (K0));

#define SWRITE(P, BUF)                                                         \
    *(s16x8*)((BUF) + dA0) = P##0;                                             \
    *(s16x8*)((BUF) + dA1) = P##1;                                             \
    *(s16x8*)((BUF) + dB0) = P##2;                                             \
    *(s16x8*)((BUF) + dB1) = P##3;

// ---------------------------------------------------------------------------
// 32x32 GEMM tile, 128 threads (2 waves; wave w owns cols w*16..+15), BK=64.
// r9-proven race-free reg-staged double-buffer pipeline: only __syncthreads +
// compiler-tracked data deps. Trailing barriers on the final step are skipped
// (uniform conditions -> no divergence hazard).
// ---------------------------------------------------------------------------
__device__ __forceinline__ void gemm3232(
    short* ldsb,                       // 2 x 8192 bytes
    const short* __restrict__ A, int ldA, int am0,
    const short* __restrict__ Wt, int ldW, int n0,
    int nsteps, int tid,
    f32x4& a0, f32x4& a1)
{
    const int w = tid >> 6, l = tid & 63;
    const int r = l & 15, hi = l >> 4;

    const int rr = tid >> 3, sl = tid & 7;
    const short* gA0 = A + (size_t)(am0 + rr) * ldA + ((sl ^ (rr & 7)) << 3);
    const short* gA1 = A + (size_t)(am0 + rr + 16) * ldA + ((sl ^ (rr & 7)) << 3);
    const short* gB0 = Wt + (size_t)(n0 + rr) * ldW + ((sl ^ (rr & 7)) << 3);
    const short* gB1 = Wt + (size_t)(n0 + rr + 16) * ldW + ((sl ^ (rr & 7)) << 3);
    const int dA0 = rr*128 + sl*16,        dA1 = (rr+16)*128 + sl*16;
    const int dB0 = 4096 + rr*128 + sl*16, dB1 = 4096 + (rr+16)*128 + sl*16;
    char* b0 = (char*)ldsb;
    char* b1 = (char*)ldsb + 8192;

    s16x8 Pa0, Pa1, Pa2, Pa3;
    s16x8 Pb0, Pb1, Pb2, Pb3;

    SLOAD(Pa, 0)
    SWRITE(Pa, b0)
    SLOAD(Pa, 64)
    __syncthreads();
    for (int s = 0; s < nsteps; s += 2) {
        if (s + 2 < nsteps) { SLOAD(Pb, 64*(s+2)) }
        mstep32(b0, w, r, hi, a0, a1);
        if (s + 1 < nsteps) {
            SWRITE(Pa, b1)
            __syncthreads();
            if (s + 3 < nsteps) { SLOAD(Pa, 64*(s+3)) }
            mstep32(b1, w, r, hi, a0, a1);
            if (s + 2 < nsteps) {
                SWRITE(Pb, b0)
                __syncthreads();
            }
        }
    }
}

// ---------------------------------------------------------------------------
// P0 (fat 64x64 tiles): weight transposes -> bf16 [n][k]; gather; width cols.
// blocks: [0,576)    four 768x768 transposes (Ws, We, Wa+Wc, Wb-Wc), 144 each
//         [576,876)  WtOut^T -> [768][1600], zero-padded rows >= 1566
//         [876,1132) gather seq -> Xg bf16 (4 rows/block)
//         [1132,1148) Xcat width-emb cols 1536..1599
// ---------------------------------------------------------------------------
__global__ __launch_bounds__(256) void k_prep(
    const float* __restrict__ seq,
    const int* __restrict__ starts, const int* __restrict__ ends,
    const float* __restrict__ Ws, const float* __restrict__ We,
    const float* __restrict__ W1, const float* __restrict__ Wout,
    const float* __restrict__ wemb,
    short* __restrict__ WtSE, short* __restrict__ WtAB,
    short* __restrict__ WtOut, short* __restrict__ Xg, short* __restrict__ Xcat)
{
    const int b = blockIdx.x;
    const int tid = threadIdx.x;

    if (b < 876) {                       // 64x64 transpose tiles
        __shared__ float tile[64][65];
        const int rr = tid >> 4;         // 0..15
        const int c4 = (tid & 15) << 2;  // 0..60

        int kt, nt, ld, sec;
        const float* srcA; const float* srcC = nullptr; float sg = 0.f;
        short* dst;
        if (b < 576) {
            sec = b / 144;
            const int t = b % 144;
            kt = t / 12; nt = t % 12; ld = H;
            dst = (sec < 2 ? WtSE : WtAB) + (size_t)(sec & 1) * H * H;
            if (sec == 0)      srcA = Ws;
            else if (sec == 1) srcA = We;
            else {
                srcA = W1 + (size_t)(sec == 2 ? 0 : H) * H;
                srcC = W1 + (size_t)2 * H * H;
                sg = (sec == 2) ? 1.f : -1.f;
            }
        } else {
            const int t = b - 576;
            nt = t / 25; kt = t % 25; ld = K2P;
            dst = WtOut; srcA = Wout;
        }

        #pragma unroll
        for (int p = 0; p < 4; ++p) {
            const int rrow = p*16 + rr;
            const int srow = kt*64 + rrow, scol = nt*64 + c4;
            float4 v = make_float4(0.f, 0.f, 0.f, 0.f);
            if (b < 576 || srow < 1566) {
                v = *(const float4*)(srcA + (size_t)srow * H + scol);
                if (srcC) {
                    float4 c = *(const float4*)(srcC + (size_t)srow * H + scol);
                    v = make_float4(fmaf(sg,c.x,v.x), fmaf(sg,c.y,v.y),
                                    fmaf(sg,c.z,v.z), fmaf(sg,c.w,v.w));
                }
            }
            tile[rrow][c4+0]=v.x; tile[rrow][c4+1]=v.y;
            tile[rrow][c4+2]=v.z; tile[rrow][c4+3]=v.w;
        }
        __syncthreads();
        #pragma unroll
        for (int p = 0; p < 4; ++p) {
            const int nn = p*16 + rr;
            short4 o;
            o.x = f2bf(tile[c4+0][nn]); o.y = f2bf(tile[c4+1][nn]);
            o.z = f2bf(tile[c4+2][nn]); o.w = f2bf(tile[c4+3][nn]);
            *(short4*)(dst + (size_t)(nt*64 + nn) * ld + kt*64 + c4) = o;
        }
    } else if (b < 1132) {               // gather: Xg[0:512)=starts, [512:1024)=ends
        const int gr = (b - 876) * 4 + (tid >> 6);
        const int c = tid & 63;
        const int spanrow = gr & 511;
        const int idx = (gr < 512) ? starts[spanrow] : ends[spanrow];
        const size_t base = ((size_t)(spanrow >> 7) * SEQLEN + idx) * H;
        #pragma unroll
        for (int i = 0; i < 12; ++i) {
            const int col = c + i*64;
            Xg[(size_t)gr * H + col] = f2bf(seq[base + col]);
        }
    } else {                             // Xcat width-emb cols 1536..1599
        const int q = b - 1132;          // 16 blocks x 32 rows
        for (int t = tid; t < 32*64; t += 256) {
            const int row = q*32 + (t >> 6), c = t & 63;
            int wd = ends[row] - starts[row];
            wd = wd < 0 ? 0 : (wd > 10 ? 10 : wd);
            Xcat[(size_t)row * K2P + 1536 + c] = (c < 30) ? f2bf(wemb[wd*30 + c]) : (short)0;
        }
    }
}

// ---------------------------------------------------------------------------
// G1: Xcat[:, gc] = Xg(half) @ WtSE^T + bias   (N = 1536, 48 col-tiles of 32)
// ---------------------------------------------------------------------------
__global__ __launch_bounds__(128) void k_g1(
    const short* __restrict__ Xg, const short* __restrict__ WtSE,
    const float* __restrict__ bs, const float* __restrict__ be,
    short* __restrict__ Xcat)
{
    __shared__ __align__(16) short lds[2][4096];
    const int tid = threadIdx.x;
    const int bm = blockIdx.x, n0 = blockIdx.y * 32;
    const int am0 = (n0 >= 768 ? 512 : 0) + bm * 32;

    f32x4 a0 = {}, a1 = {};
    gemm3232(&lds[0][0], Xg, H, am0, WtSE, H, n0, 12, tid, a0, a1);

    const int w = tid >> 6, l = tid & 63;
    const int r = l & 15, hi = l >> 4;
    const int gc = n0 + w*16 + r;
    const float bv = (gc < 768) ? bs[gc] : be[gc - 768];
    const int r0 = bm*32 + hi*4, r1 = r0 + 16;
    #pragma unroll
    for (int rg = 0; rg < 4; ++rg) {
        Xcat[(size_t)(r0 + rg) * K2P + gc] = f2bf(a0[rg] + bv);
        Xcat[(size_t)(r1 + rg) * K2P + gc] = f2bf(a1[rg] + bv);
    }
}

// ---------------------------------------------------------------------------
// G2: SR = Xcat(K=1600) @ WtOut^T + b_out   (24 col-tiles of 32)
// ---------------------------------------------------------------------------
__global__ __launch_bounds__(128) void k_g2(
    const short* __restrict__ Xcat, const short* __restrict__ WtOut,
    const float* __restrict__ bout, short* __restrict__ SR)
{
    __shared__ __align__(16) short lds[2][4096];
    const int tid = threadIdx.x;
    const int bm = blockIdx.x, n0 = blockIdx.y * 32;

    f32x4 a0 = {}, a1 = {};
    gemm3232(&lds[0][0], Xcat, K2P, bm*32, WtOut, K2P, n0, 25, tid, a0, a1);

    const int w = tid >> 6, l = tid & 63;
    const int r = l & 15, hi = l >> 4;
    const int gc = n0 + w*16 + r;
    const float bv = bout[gc];
    const int r0 = bm*32 + hi*4, r1 = r0 + 16;
    #pragma unroll
    for (int rg = 0; rg < 4; ++rg) {
        SR[(size_t)(r0 + rg) * H + gc] = f2bf(a0[rg] + bv);
        SR[(size_t)(r1 + rg) * H + gc] = f2bf(a1[rg] + bv);
    }
}

// ---------------------------------------------------------------------------
// G3: y<48: AB[:, gc] = SR @ WtAB^T (+b1 for cols<768)   [fp32 out]
//     y==48: mention = SR @ Wm + b_ment
// ---------------------------------------------------------------------------
__global__ __launch_bounds__(128) void k_g3(
    const short* __restrict__ SR, const short* __restrict__ WtAB,
    const float* __restrict__ b1, const float* __restrict__ Wm,
    const float* __restrict__ bment,
    float* __restrict__ AB, float* __restrict__ mention)
{
    const int tid = threadIdx.x;
    const int bm = blockIdx.x;

    if (blockIdx.y == 48) {               // mention scores, 32 rows per block
        const int w = tid >> 6, l = tid & 63;
        const int rows0 = bm*32 + w*16;
        const float bm_add = bment[0];
        for (int rr = 0; rr < 16; ++rr) {
            const int row = rows0 + rr;
            float p = 0.f;
            #pragma unroll
            for (int kk = 0; kk < 12; ++kk) {
                const int k = kk*64 + l;
                p = fmaf(bf2f(SR[(size_t)row * H + k]), Wm[k], p);
            }
            #pragma unroll
            for (int off = 32; off; off >>= 1) p += __shfl_down(p, off);
            if (l == 0) mention[row] = p + bm_add;
        }
        return;
    }

    __shared__ __align__(16) short lds[2][4096];
    const int n0 = blockIdx.y * 32;

    f32x4 a0 = {}, a1 = {};
    gemm3232(&lds[0][0], SR, H, bm*32, WtAB, H, n0, 12, tid, a0, a1);

    const int w = tid >> 6, l = tid & 63;
    const int r = l & 15, hi = l >> 4;
    const int gc = n0 + w*16 + r;
    const float bv = (gc < 768) ? b1[gc] : 0.f;
    const int r0 = bm*32 + hi*4, r1 = r0 + 16;
    #pragma unroll
    for (int rg = 0; rg < 4; ++rg) {
        AB[(size_t)(r0 + rg) * 1536 + gc] = a0[rg] + bv;
        AB[(size_t)(r1 + rg) * 1536 + gc] = a1[rg] + bv;
    }
}

// ---------------------------------------------------------------------------
// G4: pair[b,i,j] = (j<i) ? sum_h relu(AI+BJ)*W2[h] + b2 : 0  (r9-proven)
// ---------------------------------------------------------------------------
__global__ __launch_bounds__(256) void k_pair(
    const float* __restrict__ AB, const float* __restrict__ W2,
    const float* __restrict__ b2, float* __restrict__ pair)
{
    const int tid = threadIdx.x;
    const int bx = blockIdx.x & 7, by = blockIdx.x >> 3;
    const int bz = blockIdx.y;

    const int tx = tid & 15, ty = tid >> 4;
    const int i = by * 16 + ty, j = bx * 16 + tx;
    float* outp = pair + ((size_t)bz * NSPAN + i) * NSPAN + j;

    if (bx > by) { *outp = 0.f; return; }

    __shared__ __align__(16) float Ais[16][68];
    __shared__ __align__(16) float Bjs[16][68];
    __shared__ __align__(16) float w2s[768];
    for (int q = tid; q < 768; q += 256) w2s[q] = W2[q];

    const int sr = tid >> 4, sc = (tid & 15) << 2;
    const float* aSrc = AB + ((size_t)bz*NSPAN + by*16 + sr)*1536 + sc;
    const float* bSrc = AB + ((size_t)bz*NSPAN + bx*16 + sr)*1536 + 768 + sc;
    float acc = 0.f;

    float4 ra = *(const float4*)(aSrc);
    float4 rb = *(const float4*)(bSrc);

    for (int ch = 0; ch < 12; ++ch) {
        __syncthreads();
        *(float4*)&Ais[sr][sc] = ra;
        *(float4*)&Bjs[sr][sc] = rb;
        __syncthreads();
        if (ch < 11) {
            ra = *(const float4*)(aSrc + (ch+1)*64);
            rb = *(const float4*)(bSrc + (ch+1)*64);
        }
        #pragma unroll
        for (int hq = 0; hq < 16; ++hq) {
            float4 a = *(const float4*)&Ais[ty][hq << 2];
            float4 b = *(const float4*)&Bjs[tx][hq << 2];
            float4 wv = *(const float4*)&w2s[ch*64 + (hq << 2)];
            acc = fmaf(fmaxf(a.x + b.x, 0.f), wv.x, acc);
            acc = fmaf(fmaxf(a.y + b.y, 0.f), wv.y, acc);
            acc = fmaf(fmaxf(a.z + b.z, 0.f), wv.z, acc);
            acc = fmaf(fmaxf(a.w + b.w, 0.f), wv.w, acc);
        }
    }
    *outp = (j < i) ? (acc + b2[0]) : 0.f;
}

// ---------------------------------------------------------------------------
extern "C" void kernel_launch(void* const* d_in, const int* in_sizes, int n_in,
                              void* d_out, int out_size, void* d_ws, size_t ws_size,
                              hipStream_t stream)
{
    const float* seq    = (const float*)d_in[0];
    const int*   starts = (const int*)  d_in[1];
    const int*   ends   = (const int*)  d_in[2];
    const float* Ws     = (const float*)d_in[3];
    const float* bs     = (const float*)d_in[4];
    const float* We     = (const float*)d_in[5];
    const float* be     = (const float*)d_in[6];
    const float* wemb   = (const float*)d_in[7];
    const float* Wout   = (const float*)d_in[8];
    const float* bout   = (const float*)d_in[9];
    const float* Wm     = (const float*)d_in[10];
    const float* bment  = (const float*)d_in[11];
    const float* W1     = (const float*)d_in[12];
    const float* b1     = (const float*)d_in[13];
    const float* W2     = (const float*)d_in[14];
    const float* b2     = (const float*)d_in[15];

    float* ws = (float*)d_ws;
    float* AB    = ws;                          // 512*1536 fp32
    short* Xg    = (short*)(ws + 786432);       // 1024*768 bf16
    short* Xcat  = Xg + 786432;                 // 512*1600 bf16
    short* SR    = Xcat + 819200;               // 512*768  bf16
    short* WtSE  = SR + 393216;                 // 1536*768 bf16
    short* WtAB  = WtSE + 1179648;              // 1536*768 bf16
    short* WtOut = WtAB + 1179648;              // 768*1600 bf16

    float* out_mention = (float*)d_out;         // 512
    float* out_pair    = (float*)d_out + 512;   // 4*128*128

    hipLaunchKernelGGL(k_prep, dim3(1148), dim3(256), 0, stream,
                       seq, starts, ends, Ws, We, W1, Wout, wemb,
                       WtSE, WtAB, WtOut, Xg, Xcat);
    hipLaunchKernelGGL(k_g1, dim3(16, 48), dim3(128), 0, stream,
                       Xg, WtSE, bs, be, Xcat);
    hipLaunchKernelGGL(k_g2, dim3(16, 24), dim3(128), 0, stream,
                       Xcat, WtOut, bout, SR);
    hipLaunchKernelGGL(k_g3, dim3(16, 49), dim3(128), 0, stream,
                       SR, WtAB, b1, Wm, bment, AB, out_mention);
    hipLaunchKernelGGL(k_pair, dim3(64, 4), dim3(256), 0, stream,
                       AB, W2, b2, out_pair);
}